// Round 1
// baseline (211.556 us; speedup 1.0000x reference)
//
#include <hip/hip_runtime.h>

#define EPSV 1e-5f

typedef float f4 __attribute__((ext_vector_type(4)));

// Problem constants (match setup_inputs)
#define B   16
#define CIN 3
#define C1  64
#define C   256
#define H   128
#define W   128
#define K   5
#define KK  25

// ---------------------------------------------------------------------------
// Kernel 1: Conv2d(3->64,3x3,zero-pad 1) + bias + BN(eval) + ReLU, reduced to
// per-(b,chunk,channel) partial sums for the global average pool.
// Block: 256 thr = 8 rows x 32 channel-groups (2 ch/thread). Grid: B * (H/8).
// ---------------------------------------------------------------------------
#define R1  8
#define CH1 (H / R1)        // 16 row-chunks
#define TW1 132             // tile col c  <->  global col (c-1); zero-padded

__global__ __launch_bounds__(256) void k1_conv_pool(
    const float* __restrict__ raw, const float* __restrict__ wconv,
    const float* __restrict__ bconv, const float* __restrict__ g1,
    const float* __restrict__ be1, const float* __restrict__ m1,
    const float* __restrict__ v1, float* __restrict__ partial)
{
  const int b     = blockIdx.x >> 4;   // CH1 == 16
  const int chunk = blockIdx.x & 15;
  const int tid   = threadIdx.x;

  __shared__ __align__(16) float tile[CIN][R1 + 2][TW1];
  const float* rawb = raw + (size_t)b * CIN * H * W;
  for (int i = tid; i < CIN * (R1 + 2) * TW1; i += 256) {
    int ic  = i / ((R1 + 2) * TW1);
    int rem = i - ic * (R1 + 2) * TW1;
    int r   = rem / TW1;
    int cc  = rem - r * TW1;
    int gr  = chunk * R1 + r - 1;
    int gc  = cc - 1;
    float val = 0.f;
    if ((unsigned)gr < H && (unsigned)gc < W)
      val = rawb[ic * H * W + gr * W + gc];
    tile[ic][r][cc] = val;
  }
  __syncthreads();

  const int row = tid >> 5;   // 0..7
  const int grp = tid & 31;   // channels 2*grp, 2*grp+1
  float wt[2][27], bias[2], sc[2], mn[2], bt[2];
#pragma unroll
  for (int g = 0; g < 2; ++g) {
    int c = grp * 2 + g;
#pragma unroll
    for (int k = 0; k < 27; ++k) wt[g][k] = wconv[c * 27 + k];
    bias[g] = bconv[c];
    sc[g]   = g1[c] * rsqrtf(v1[c] + EPSV);
    mn[g]   = m1[c];
    bt[g]   = be1[c];
  }

  float acc0 = 0.f, acc1 = 0.f;
  for (int w = 0; w < W; w += 4) {
    float v[2][4];
#pragma unroll
    for (int p = 0; p < 4; ++p) { v[0][p] = bias[0]; v[1][p] = bias[1]; }
#pragma unroll
    for (int ic = 0; ic < CIN; ++ic) {
#pragma unroll
      for (int kh = 0; kh < 3; ++kh) {
        f4 a  = *(const f4*)&tile[ic][row + kh][w];
        f4 bb = *(const f4*)&tile[ic][row + kh][w + 4];
#pragma unroll
        for (int p = 0; p < 4; ++p) {
#pragma unroll
          for (int kw = 0; kw < 3; ++kw) {
            float e = (p + kw < 4) ? a[p + kw] : bb[p + kw - 4];
            v[0][p] += e * wt[0][ic * 9 + kh * 3 + kw];
            v[1][p] += e * wt[1][ic * 9 + kh * 3 + kw];
          }
        }
      }
    }
#pragma unroll
    for (int p = 0; p < 4; ++p) {
      acc0 += fmaxf((v[0][p] - mn[0]) * sc[0] + bt[0], 0.f);
      acc1 += fmaxf((v[1][p] - mn[1]) * sc[1] + bt[1], 0.f);
    }
  }

  __shared__ float red[R1][C1];
  red[row][grp * 2]     = acc0;
  red[row][grp * 2 + 1] = acc1;
  __syncthreads();
  if (tid < C1) {
    float s = 0.f;
#pragma unroll
    for (int r = 0; r < R1; ++r) s += red[r][tid];
    partial[((size_t)b * CH1 + chunk) * C1 + tid] = s;
  }
}

// ---------------------------------------------------------------------------
// Kernel 2: img_feat mean -> dense (1x1 conv) + bias + BN -> softmax over C.
// Block (b, kk): 256 threads = 256 channels. Grid: B * KK.
// ---------------------------------------------------------------------------
__global__ __launch_bounds__(256) void k2_filter(
    const float* __restrict__ partial, const float* __restrict__ wf,
    const float* __restrict__ bf, const float* __restrict__ g2,
    const float* __restrict__ be2, const float* __restrict__ m2,
    const float* __restrict__ v2, float* __restrict__ filt)
{
  const int b  = blockIdx.x / KK;
  const int kk = blockIdx.x - b * KK;
  const int c  = threadIdx.x;

  __shared__ float feat[C1];
  if (c < C1) {
    float s = 0.f;
#pragma unroll
    for (int ch = 0; ch < CH1; ++ch)
      s += partial[((size_t)b * CH1 + ch) * C1 + c];
    feat[c] = s * (1.f / (H * W));
  }
  __syncthreads();

  const int idx = c * KK + kk;
  float v = bf[idx];
  const float* wr = wf + (size_t)idx * C1;
#pragma unroll
  for (int j = 0; j < C1; ++j) v += feat[j] * wr[j];
  v = (v - m2[idx]) * (g2[idx] * rsqrtf(v2[idx] + EPSV)) + be2[idx];

  __shared__ float red[256];
  red[c] = v;
  __syncthreads();
#pragma unroll
  for (int s = 128; s > 0; s >>= 1) {
    if (c < s) red[c] = fmaxf(red[c], red[c + s]);
    __syncthreads();
  }
  float mx = red[0];
  __syncthreads();
  float e = expf(v - mx);
  red[c] = e;
  __syncthreads();
#pragma unroll
  for (int s = 128; s > 0; s >>= 1) {
    if (c < s) red[c] += red[c + s];
    __syncthreads();
  }
  filt[((size_t)b * C + c) * KK + kk] = e / red[0];
}

// ---------------------------------------------------------------------------
// Kernel 3: per-sample dynamic depthwise 5x5 conv, reflect pad 2.
// Block: one (b,c,row-tile of 16). 256 thr, 2 four-pixel groups each.
// Grid: B*C*(H/16) = 32768.
// ---------------------------------------------------------------------------
#define R3  16
#define TW3 132             // tile col c <-> global col (c-2), reflect-mapped

__global__ __launch_bounds__(256) void k3_dwconv(
    const float* __restrict__ x, const float* __restrict__ filt,
    float* __restrict__ out)
{
  const int tile_i = blockIdx.x & 7;      // H/R3 == 8
  const int plane  = blockIdx.x >> 3;     // b*C + c
  const float* xp = x + (size_t)plane * H * W;
  float* op       = out + (size_t)plane * H * W;
  const float* fp = filt + (size_t)plane * KK;
  const int tid   = threadIdx.x;
  const int r0    = tile_i * R3;

  __shared__ __align__(16) float t[R3 + 4][TW3];
  for (int i = tid; i < (R3 + 4) * TW3; i += 256) {
    int r  = i / TW3;
    int cc = i - r * TW3;
    int gr = r0 + r - 2;
    gr = gr < 0 ? -gr : (gr >= H ? 2 * H - 2 - gr : gr);
    int gc = cc - 2;
    gc = gc < 0 ? -gc : (gc >= W ? 2 * W - 2 - gc : gc);
    t[r][cc] = xp[gr * W + gc];
  }
  float f[KK];
#pragma unroll
  for (int k = 0; k < KK; ++k) f[k] = fp[k];
  __syncthreads();

#pragma unroll
  for (int q = 0; q < 2; ++q) {
    int k = tid + q * 256;        // 0..511
    int r = k >> 5;               // 0..15
    int w = (k & 31) * 4;         // 0..124
    f4 acc = {0.f, 0.f, 0.f, 0.f};
#pragma unroll
    for (int i = 0; i < K; ++i) {
      f4 a  = *(const f4*)&t[r + i][w];
      f4 bb = *(const f4*)&t[r + i][w + 4];
#pragma unroll
      for (int p = 0; p < 4; ++p) {
#pragma unroll
        for (int j = 0; j < K; ++j) {
          float e = (p + j < 4) ? a[p + j] : bb[p + j - 4];
          acc[p] += e * f[i * K + j];
        }
      }
    }
    *(f4*)&op[(r0 + r) * W + w] = acc;
  }
}

// ---------------------------------------------------------------------------
extern "C" void kernel_launch(void* const* d_in, const int* in_sizes, int n_in,
                              void* d_out, int out_size, void* d_ws, size_t ws_size,
                              hipStream_t stream) {
  const float* x_feat = (const float*)d_in[0];
  const float* raw    = (const float*)d_in[1];
  const float* wconv  = (const float*)d_in[2];
  const float* bconv  = (const float*)d_in[3];
  const float* g1     = (const float*)d_in[4];
  const float* be1    = (const float*)d_in[5];
  const float* m1     = (const float*)d_in[6];
  const float* v1     = (const float*)d_in[7];
  const float* wf     = (const float*)d_in[8];
  const float* bf     = (const float*)d_in[9];
  const float* g2     = (const float*)d_in[10];
  const float* be2    = (const float*)d_in[11];
  const float* m2     = (const float*)d_in[12];
  const float* v2     = (const float*)d_in[13];
  float* out = (float*)d_out;

  float* partial = (float*)d_ws;                    // B*CH1*C1 floats
  float* filt    = partial + B * CH1 * C1;          // B*C*KK floats

  k1_conv_pool<<<B * CH1, 256, 0, stream>>>(raw, wconv, bconv, g1, be1, m1, v1, partial);
  k2_filter  <<<B * KK, 256, 0, stream>>>(partial, wf, bf, g2, be2, m2, v2, filt);
  k3_dwconv  <<<B * C * (H / R3), 256, 0, stream>>>(x_feat, filt, out);
}

// Round 2
// 138.822 us; speedup vs baseline: 1.5239x; 1.5239x over previous
//
#include <hip/hip_runtime.h>

#define EPSV 1e-5f

typedef float f4 __attribute__((ext_vector_type(4)));
typedef float f2 __attribute__((ext_vector_type(2)));

// Problem constants (match setup_inputs)
#define B   16
#define CIN 3
#define C1  64
#define C   256
#define H   128
#define W   128
#define K   5
#define KK  25
#define FSTR 28            // padded filter stride (16B-aligned f4 loads)

// ---------------------------------------------------------------------------
// Kernel 1: Conv2d(3->64,3x3,zero-pad 1) + bias + BN(eval) + ReLU, reduced to
// per-(b,chunk,channel) partial sums for the global average pool.
// ---------------------------------------------------------------------------
#define R1  8
#define CH1 (H / R1)        // 16 row-chunks
#define TW1 132

__global__ __launch_bounds__(256) void k1_conv_pool(
    const float* __restrict__ raw, const float* __restrict__ wconv,
    const float* __restrict__ bconv, const float* __restrict__ g1,
    const float* __restrict__ be1, const float* __restrict__ m1,
    const float* __restrict__ v1, float* __restrict__ partial)
{
  const int b     = blockIdx.x >> 4;
  const int chunk = blockIdx.x & 15;
  const int tid   = threadIdx.x;

  __shared__ __align__(16) float tile[CIN][R1 + 2][TW1];
  const float* rawb = raw + (size_t)b * CIN * H * W;
  for (int i = tid; i < CIN * (R1 + 2) * TW1; i += 256) {
    int ic  = i / ((R1 + 2) * TW1);
    int rem = i - ic * (R1 + 2) * TW1;
    int r   = rem / TW1;
    int cc  = rem - r * TW1;
    int gr  = chunk * R1 + r - 1;
    int gc  = cc - 1;
    float val = 0.f;
    if ((unsigned)gr < H && (unsigned)gc < W)
      val = rawb[ic * H * W + gr * W + gc];
    tile[ic][r][cc] = val;
  }
  __syncthreads();

  const int row = tid >> 5;
  const int grp = tid & 31;
  float wt[2][27], bias[2], sc[2], mn[2], bt[2];
#pragma unroll
  for (int g = 0; g < 2; ++g) {
    int c = grp * 2 + g;
#pragma unroll
    for (int k = 0; k < 27; ++k) wt[g][k] = wconv[c * 27 + k];
    bias[g] = bconv[c];
    sc[g]   = g1[c] * rsqrtf(v1[c] + EPSV);
    mn[g]   = m1[c];
    bt[g]   = be1[c];
  }

  float acc0 = 0.f, acc1 = 0.f;
  for (int w = 0; w < W; w += 4) {
    float v[2][4];
#pragma unroll
    for (int p = 0; p < 4; ++p) { v[0][p] = bias[0]; v[1][p] = bias[1]; }
#pragma unroll
    for (int ic = 0; ic < CIN; ++ic) {
#pragma unroll
      for (int kh = 0; kh < 3; ++kh) {
        f4 a  = *(const f4*)&tile[ic][row + kh][w];
        f4 bb = *(const f4*)&tile[ic][row + kh][w + 4];
#pragma unroll
        for (int p = 0; p < 4; ++p) {
#pragma unroll
          for (int kw = 0; kw < 3; ++kw) {
            float e = (p + kw < 4) ? a[p + kw] : bb[p + kw - 4];
            v[0][p] += e * wt[0][ic * 9 + kh * 3 + kw];
            v[1][p] += e * wt[1][ic * 9 + kh * 3 + kw];
          }
        }
      }
    }
#pragma unroll
    for (int p = 0; p < 4; ++p) {
      acc0 += fmaxf((v[0][p] - mn[0]) * sc[0] + bt[0], 0.f);
      acc1 += fmaxf((v[1][p] - mn[1]) * sc[1] + bt[1], 0.f);
    }
  }

  __shared__ float red[R1][C1];
  red[row][grp * 2]     = acc0;
  red[row][grp * 2 + 1] = acc1;
  __syncthreads();
  if (tid < C1) {
    float s = 0.f;
#pragma unroll
    for (int r = 0; r < R1; ++r) s += red[r][tid];
    partial[((size_t)b * CH1 + chunk) * C1 + tid] = s;
  }
}

// ---------------------------------------------------------------------------
// Kernel 2: pool mean -> dense + BN -> softmax over C. Writes padded stride 28.
// ---------------------------------------------------------------------------
__global__ __launch_bounds__(256) void k2_filter(
    const float* __restrict__ partial, const float* __restrict__ wf,
    const float* __restrict__ bf, const float* __restrict__ g2,
    const float* __restrict__ be2, const float* __restrict__ m2,
    const float* __restrict__ v2, float* __restrict__ filt)
{
  const int b  = blockIdx.x / KK;
  const int kk = blockIdx.x - b * KK;
  const int c  = threadIdx.x;

  __shared__ float feat[C1];
  if (c < C1) {
    float s = 0.f;
#pragma unroll
    for (int ch = 0; ch < CH1; ++ch)
      s += partial[((size_t)b * CH1 + ch) * C1 + c];
    feat[c] = s * (1.f / (H * W));
  }
  __syncthreads();

  const int idx = c * KK + kk;
  float v = bf[idx];
  const float* wr = wf + (size_t)idx * C1;
#pragma unroll
  for (int j = 0; j < C1; ++j) v += feat[j] * wr[j];
  v = (v - m2[idx]) * (g2[idx] * rsqrtf(v2[idx] + EPSV)) + be2[idx];

  __shared__ float red[256];
  red[c] = v;
  __syncthreads();
#pragma unroll
  for (int s = 128; s > 0; s >>= 1) {
    if (c < s) red[c] = fmaxf(red[c], red[c + s]);
    __syncthreads();
  }
  float mx = red[0];
  __syncthreads();
  float e = expf(v - mx);
  red[c] = e;
  __syncthreads();
#pragma unroll
  for (int s = 128; s > 0; s >>= 1) {
    if (c < s) red[c] += red[c + s];
    __syncthreads();
  }
  filt[((size_t)b * C + c) * FSTR + kk] = e / red[0];
}

// ---------------------------------------------------------------------------
// Kernel 3: per-sample dynamic depthwise 5x5 conv, reflect pad 2.
// 32-row x 128-col tile, 512 threads, 2 output rows x 4 cols per thread.
// Filter in 7 f4 registers (static indexing). f4 staging, nontemporal stores.
// Grid 16384, XCD-chunk swizzled.
// ---------------------------------------------------------------------------
#define R3  32
#define TW3 132
#define TH3 (R3 + 4)        // 36 tile rows

__global__ __launch_bounds__(512) void k3_dwconv(
    const float* __restrict__ x, const float* __restrict__ filt,
    float* __restrict__ out)
{
  const int bid = blockIdx.x;
  const int swz = (bid & 7) * 2048 + (bid >> 3);   // 16384 % 8 == 0, bijective
  const int plane = swz >> 2;                       // b*C + c
  const int tile  = swz & 3;
  const int r0    = tile * R3;
  const int tid   = threadIdx.x;

  const float* xp = x + (size_t)plane * H * W;
  float* op       = out + (size_t)plane * H * W;
  const float* fp = filt + (size_t)plane * FSTR;

  // filter -> 7 f4 registers (16B aligned thanks to FSTR=28)
  f4 fv[7];
#pragma unroll
  for (int i = 0; i < 7; ++i) fv[i] = *(const f4*)&fp[i << 2];

  __shared__ __align__(16) float t[TH3][TW3];

  // interior staging: 36 rows x 32 f4-groups, reflect rows
  for (int idx = tid; idx < TH3 * 32; idx += 512) {
    int r = idx >> 5, g = idx & 31;
    int gr = r0 + r - 2;
    gr = gr < 0 ? -gr : (gr >= H ? 2 * H - 2 - gr : gr);
    f4 v = *(const f4*)&xp[gr * W + (g << 2)];
    f2 lo = {v[0], v[1]};
    f2 hi = {v[2], v[3]};
    *(f2*)&t[r][(g << 2) + 2] = lo;   // 8B-aligned ds_write_b64
    *(f2*)&t[r][(g << 2) + 4] = hi;
  }
  // column halo: 36 rows x 4 cols (reflect cols)
  if (tid < TH3 * 4) {
    int r = tid >> 2, c = tid & 3;
    int cc = (c == 0) ? 0 : (c == 1) ? 1 : (c == 2) ? 130 : 131;
    int gc = (c == 0) ? 2 : (c == 1) ? 1 : (c == 2) ? 126 : 125;
    int gr = r0 + r - 2;
    gr = gr < 0 ? -gr : (gr >= H ? 2 * H - 2 - gr : gr);
    t[r][cc] = xp[gr * W + gc];
  }
  __syncthreads();

  const int g  = tid & 31, w = g << 2;
  const int rb = (tid >> 5) << 1;          // output rows rb, rb+1 (within tile)
  f4 acc0 = {0.f, 0.f, 0.f, 0.f};
  f4 acc1 = {0.f, 0.f, 0.f, 0.f};
#pragma unroll
  for (int i = 0; i < 6; ++i) {            // tap tile rows rb..rb+5
    f4 a  = *(const f4*)&t[rb + i][w];
    f4 bb = *(const f4*)&t[rb + i][w + 4];
#pragma unroll
    for (int p = 0; p < 4; ++p) {
#pragma unroll
      for (int j = 0; j < 5; ++j) {
        float e = (p + j < 4) ? a[p + j] : bb[p + j - 4];
        if (i <= 4) {
          const int k0 = i * 5 + j;
          acc0[p] += e * fv[k0 >> 2][k0 & 3];
        }
        if (i >= 1) {
          const int k1 = (i - 1) * 5 + j;
          acc1[p] += e * fv[k1 >> 2][k1 & 3];
        }
      }
    }
  }
  __builtin_nontemporal_store(acc0, (f4*)&op[(r0 + rb) * W + w]);
  __builtin_nontemporal_store(acc1, (f4*)&op[(r0 + rb + 1) * W + w]);
}

// ---------------------------------------------------------------------------
extern "C" void kernel_launch(void* const* d_in, const int* in_sizes, int n_in,
                              void* d_out, int out_size, void* d_ws, size_t ws_size,
                              hipStream_t stream) {
  const float* x_feat = (const float*)d_in[0];
  const float* raw    = (const float*)d_in[1];
  const float* wconv  = (const float*)d_in[2];
  const float* bconv  = (const float*)d_in[3];
  const float* g1     = (const float*)d_in[4];
  const float* be1    = (const float*)d_in[5];
  const float* m1     = (const float*)d_in[6];
  const float* v1     = (const float*)d_in[7];
  const float* wf     = (const float*)d_in[8];
  const float* bf     = (const float*)d_in[9];
  const float* g2     = (const float*)d_in[10];
  const float* be2    = (const float*)d_in[11];
  const float* m2     = (const float*)d_in[12];
  const float* v2     = (const float*)d_in[13];
  float* out = (float*)d_out;

  float* partial = (float*)d_ws;                    // B*CH1*C1 floats
  float* filt    = partial + B * CH1 * C1;          // B*C*FSTR floats

  k1_conv_pool<<<B * CH1, 256, 0, stream>>>(raw, wconv, bconv, g1, be1, m1, v1, partial);
  k2_filter  <<<B * KK, 256, 0, stream>>>(partial, wf, bf, g2, be2, m2, v2, filt);
  k3_dwconv  <<<B * C * (H / R3), 512, 0, stream>>>(x_feat, filt, out);
}

// Round 3
// 128.829 us; speedup vs baseline: 1.6421x; 1.0776x over previous
//
#include <hip/hip_runtime.h>

#define EPSV 1e-5f

typedef float f4 __attribute__((ext_vector_type(4)));
typedef float f2 __attribute__((ext_vector_type(2)));

// Problem constants (match setup_inputs)
#define B   16
#define CIN 3
#define C1  64
#define C   256
#define H   128
#define W   128
#define K   5
#define KK  25
#define FSTR 28            // padded filter stride (16B-aligned f4 loads)

// ---------------------------------------------------------------------------
// Kernel 1: Conv2d(3->64,3x3,zero-pad 1) + bias + BN(eval) + ReLU -> partial
// sums for global avg pool. Grid: 16 b x 16 row-chunks x 4 col-splits = 1024
// blocks (4/CU). Block: 128 thr = 4 row-pairs x 32 ch-pairs. Each thread:
// 2 channels x 2 rows x 32 cols, sliding-window f4 carry (12 fresh ds_read_b128
// per 4-px group serving 16 px*ch).
// ---------------------------------------------------------------------------
#define R1   8               // rows per chunk
#define WS1  32              // cols per split
#define TW1  36              // 34 used (32 + 1 halo each side), pad to 36

__global__ __launch_bounds__(128) void k1_conv_pool(
    const float* __restrict__ raw, const float* __restrict__ wconv,
    const float* __restrict__ bconv, const float* __restrict__ g1,
    const float* __restrict__ be1, const float* __restrict__ m1,
    const float* __restrict__ v1, float* __restrict__ partial)
{
  const int bid   = blockIdx.x;
  const int b     = bid >> 6;
  const int chunk = (bid >> 2) & 15;
  const int wh    = bid & 3;
  const int tid   = threadIdx.x;

  __shared__ __align__(16) float t[CIN][R1 + 2][TW1];
  const float* rawb = raw + (size_t)b * CIN * H * W;
  for (int i = tid; i < CIN * (R1 + 2) * 34; i += 128) {
    int ic  = i / ((R1 + 2) * 34);
    int rem = i - ic * (R1 + 2) * 34;
    int r   = rem / 34;
    int cc  = rem - r * 34;
    int gr  = chunk * R1 + r - 1;
    int gc  = wh * WS1 + cc - 1;
    float val = 0.f;
    if ((unsigned)gr < H && (unsigned)gc < W)
      val = rawb[ic * H * W + gr * W + gc];
    t[ic][r][cc] = val;
  }
  __syncthreads();

  const int rp  = tid >> 5;        // row-pair 0..3 -> output rows 2rp,2rp+1
  const int grp = tid & 31;        // channels 2grp, 2grp+1
  float wt[2][27], A[2], Bc[2];
#pragma unroll
  for (int g = 0; g < 2; ++g) {
    int c = grp * 2 + g;
#pragma unroll
    for (int k = 0; k < 27; ++k) wt[g][k] = wconv[c * 27 + k];
    float sc = g1[c] * rsqrtf(v1[c] + EPSV);
    A[g]  = sc;
    Bc[g] = (bconv[c] - m1[c]) * sc + be1[c];
  }

  // sliding window: cur/nxt[ic][r], r = tap tile rows 2rp .. 2rp+3
  f4 cur[CIN][4], nxt[CIN][4];
#pragma unroll
  for (int ic = 0; ic < CIN; ++ic)
#pragma unroll
    for (int r = 0; r < 4; ++r) cur[ic][r] = *(const f4*)&t[ic][2 * rp + r][0];

  float acc0 = 0.f, acc1 = 0.f;
#pragma unroll
  for (int j = 0; j < 8; ++j) {          // 8 groups of 4 cols
#pragma unroll
    for (int ic = 0; ic < CIN; ++ic)
#pragma unroll
      for (int r = 0; r < 4; ++r) nxt[ic][r] = *(const f4*)&t[ic][2 * rp + r][4 * j + 4];

    float v[2][2][4];                    // [q][g][p]
#pragma unroll
    for (int q = 0; q < 2; ++q)
#pragma unroll
      for (int g = 0; g < 2; ++g)
#pragma unroll
        for (int p = 0; p < 4; ++p) v[q][g][p] = 0.f;

#pragma unroll
    for (int ic = 0; ic < CIN; ++ic) {
#pragma unroll
      for (int q = 0; q < 2; ++q) {
#pragma unroll
        for (int kh = 0; kh < 3; ++kh) {
          f4 a  = cur[ic][q + kh];
          f4 bb = nxt[ic][q + kh];
#pragma unroll
          for (int p = 0; p < 4; ++p) {
#pragma unroll
            for (int kw = 0; kw < 3; ++kw) {
              float e = (p + kw < 4) ? a[p + kw] : bb[p + kw - 4];
              v[q][0][p] += e * wt[0][ic * 9 + kh * 3 + kw];
              v[q][1][p] += e * wt[1][ic * 9 + kh * 3 + kw];
            }
          }
        }
      }
    }
#pragma unroll
    for (int q = 0; q < 2; ++q)
#pragma unroll
      for (int p = 0; p < 4; ++p) {
        acc0 += fmaxf(v[q][0][p] * A[0] + Bc[0], 0.f);
        acc1 += fmaxf(v[q][1][p] * A[1] + Bc[1], 0.f);
      }
#pragma unroll
    for (int ic = 0; ic < CIN; ++ic)
#pragma unroll
      for (int r = 0; r < 4; ++r) cur[ic][r] = nxt[ic][r];
  }

  __shared__ float red[4][C1];
  red[rp][grp * 2]     = acc0;
  red[rp][grp * 2 + 1] = acc1;
  __syncthreads();
  if (tid < C1) {
    float s = red[0][tid] + red[1][tid] + red[2][tid] + red[3][tid];
    partial[((size_t)((b * 16 + chunk) * 4 + wh)) * C1 + tid] = s;
  }
}

// ---------------------------------------------------------------------------
// Kernel 2: pool mean -> dense + BN -> softmax over C. Writes padded stride 28.
// ---------------------------------------------------------------------------
#define NCH 64               // 16 chunks x 4 col-splits partial blocks per b

__global__ __launch_bounds__(256) void k2_filter(
    const float* __restrict__ partial, const float* __restrict__ wf,
    const float* __restrict__ bf, const float* __restrict__ g2,
    const float* __restrict__ be2, const float* __restrict__ m2,
    const float* __restrict__ v2, float* __restrict__ filt)
{
  const int b  = blockIdx.x / KK;
  const int kk = blockIdx.x - b * KK;
  const int c  = threadIdx.x;

  __shared__ float feat[C1];
  if (c < C1) {
    float s = 0.f;
#pragma unroll
    for (int ch = 0; ch < NCH; ++ch)
      s += partial[((size_t)b * NCH + ch) * C1 + c];
    feat[c] = s * (1.f / (H * W));
  }
  __syncthreads();

  const int idx = c * KK + kk;
  float v = bf[idx];
  const float* wr = wf + (size_t)idx * C1;
#pragma unroll
  for (int j = 0; j < C1; ++j) v += feat[j] * wr[j];
  v = (v - m2[idx]) * (g2[idx] * rsqrtf(v2[idx] + EPSV)) + be2[idx];

  __shared__ float red[256];
  red[c] = v;
  __syncthreads();
#pragma unroll
  for (int s = 128; s > 0; s >>= 1) {
    if (c < s) red[c] = fmaxf(red[c], red[c + s]);
    __syncthreads();
  }
  float mx = red[0];
  __syncthreads();
  float e = expf(v - mx);
  red[c] = e;
  __syncthreads();
#pragma unroll
  for (int s = 128; s > 0; s >>= 1) {
    if (c < s) red[c] += red[c + s];
    __syncthreads();
  }
  filt[((size_t)b * C + c) * FSTR + kk] = e / red[0];
}

// ---------------------------------------------------------------------------
// Kernel 3: per-sample dynamic depthwise 5x5 conv, reflect pad 2.
// 64-row x 128-col tile (halo 6.25%), 512 threads, 4 output rows x 4 cols per
// thread (1.0 ds_read_b128 per px). Filter in 7 f4 regs. NT stores.
// Grid 8192, XCD-chunk swizzled (plane's 2 tiles adjacent on one XCD).
// ---------------------------------------------------------------------------
#define R3  64
#define TW3 132
#define TH3 (R3 + 4)        // 68 tile rows

__global__ __launch_bounds__(512) void k3_dwconv(
    const float* __restrict__ x, const float* __restrict__ filt,
    float* __restrict__ out)
{
  const int bid = blockIdx.x;
  const int swz = (bid & 7) * 1024 + (bid >> 3);   // 8192 % 8 == 0, bijective
  const int plane = swz >> 1;                       // b*C + c
  const int tile  = swz & 1;
  const int r0    = tile * R3;
  const int tid   = threadIdx.x;

  const float* xp = x + (size_t)plane * H * W;
  float* op       = out + (size_t)plane * H * W;
  const float* fp = filt + (size_t)plane * FSTR;

  f4 fv[7];
#pragma unroll
  for (int i = 0; i < 7; ++i) fv[i] = *(const f4*)&fp[i << 2];

  __shared__ __align__(16) float t[TH3][TW3];

  // interior staging: 68 rows x 32 f4-groups, reflect rows
#pragma unroll
  for (int idx = tid; idx < TH3 * 32; idx += 512) {
    int r = idx >> 5, g = idx & 31;
    int gr = r0 + r - 2;
    gr = gr < 0 ? -gr : (gr >= H ? 2 * H - 2 - gr : gr);
    f4 v = *(const f4*)&xp[gr * W + (g << 2)];
    f2 lo = {v[0], v[1]};
    f2 hi = {v[2], v[3]};
    *(f2*)&t[r][(g << 2) + 2] = lo;
    *(f2*)&t[r][(g << 2) + 4] = hi;
  }
  // column halo: 68 rows x 4 cols (reflect cols)
  if (tid < TH3 * 4) {
    int r = tid >> 2, c = tid & 3;
    int cc = (c == 0) ? 0 : (c == 1) ? 1 : (c == 2) ? 130 : 131;
    int gc = (c == 0) ? 2 : (c == 1) ? 1 : (c == 2) ? 126 : 125;
    int gr = r0 + r - 2;
    gr = gr < 0 ? -gr : (gr >= H ? 2 * H - 2 - gr : gr);
    t[r][cc] = xp[gr * W + gc];
  }
  __syncthreads();

  const int g  = tid & 31, w = g << 2;
  const int rb = (tid >> 5) << 2;          // output rows rb..rb+3 (within tile)
  f4 acc[4];
#pragma unroll
  for (int q = 0; q < 4; ++q) acc[q] = (f4){0.f, 0.f, 0.f, 0.f};

#pragma unroll
  for (int tr = 0; tr < 8; ++tr) {         // tap tile rows rb..rb+7
    f4 a  = *(const f4*)&t[rb + tr][w];
    f4 bb = *(const f4*)&t[rb + tr][w + 4];
#pragma unroll
    for (int q = 0; q < 4; ++q) {
      if (tr - q < 0 || tr - q > 4) continue;
      const int ki = tr - q;               // kernel row
#pragma unroll
      for (int p = 0; p < 4; ++p) {
#pragma unroll
        for (int j = 0; j < 5; ++j) {
          float e = (p + j < 4) ? a[p + j] : bb[p + j - 4];
          const int k = ki * 5 + j;
          acc[q][p] += e * fv[k >> 2][k & 3];
        }
      }
    }
  }
#pragma unroll
  for (int q = 0; q < 4; ++q)
    __builtin_nontemporal_store(acc[q], (f4*)&op[(r0 + rb + q) * W + w]);
}

// ---------------------------------------------------------------------------
extern "C" void kernel_launch(void* const* d_in, const int* in_sizes, int n_in,
                              void* d_out, int out_size, void* d_ws, size_t ws_size,
                              hipStream_t stream) {
  const float* x_feat = (const float*)d_in[0];
  const float* raw    = (const float*)d_in[1];
  const float* wconv  = (const float*)d_in[2];
  const float* bconv  = (const float*)d_in[3];
  const float* g1     = (const float*)d_in[4];
  const float* be1    = (const float*)d_in[5];
  const float* m1     = (const float*)d_in[6];
  const float* v1     = (const float*)d_in[7];
  const float* wf     = (const float*)d_in[8];
  const float* bf     = (const float*)d_in[9];
  const float* g2     = (const float*)d_in[10];
  const float* be2    = (const float*)d_in[11];
  const float* m2     = (const float*)d_in[12];
  const float* v2     = (const float*)d_in[13];
  float* out = (float*)d_out;

  float* partial = (float*)d_ws;                    // B*NCH*C1 floats
  float* filt    = partial + B * NCH * C1;          // B*C*FSTR floats

  k1_conv_pool<<<B * 16 * 4, 128, 0, stream>>>(raw, wconv, bconv, g1, be1, m1, v1, partial);
  k2_filter  <<<B * KK, 256, 0, stream>>>(partial, wf, bf, g2, be2, m2, v2, filt);
  k3_dwconv  <<<B * C * (H / R3), 512, 0, stream>>>(x_feat, filt, out);
}

// Round 4
// 123.467 us; speedup vs baseline: 1.7135x; 1.0434x over previous
//
#include <hip/hip_runtime.h>

#define EPSV 1e-5f

typedef float f4 __attribute__((ext_vector_type(4)));
typedef float f2 __attribute__((ext_vector_type(2)));

// Problem constants (match setup_inputs)
#define B   16
#define CIN 3
#define C1  64
#define C   256
#define H   128
#define W   128
#define K   5
#define KK  25
#define FSTR 28            // padded filter stride (16B-aligned f4 loads)

// ---------------------------------------------------------------------------
// Kernel 1: Conv2d(3->64,3x3,zero-pad 1) + bias + BN(eval) + ReLU -> partial
// sums for global avg pool. Grid 1024 blocks x 128 thr.
// ---------------------------------------------------------------------------
#define R1   8               // rows per chunk
#define WS1  32              // cols per split
#define TW1  36

__global__ __launch_bounds__(128) void k1_conv_pool(
    const float* __restrict__ raw, const float* __restrict__ wconv,
    const float* __restrict__ bconv, const float* __restrict__ g1,
    const float* __restrict__ be1, const float* __restrict__ m1,
    const float* __restrict__ v1, float* __restrict__ partial)
{
  const int bid   = blockIdx.x;
  const int b     = bid >> 6;
  const int chunk = (bid >> 2) & 15;
  const int wh    = bid & 3;
  const int tid   = threadIdx.x;

  __shared__ __align__(16) float t[CIN][R1 + 2][TW1];
  const float* rawb = raw + (size_t)b * CIN * H * W;
  for (int i = tid; i < CIN * (R1 + 2) * 34; i += 128) {
    int ic  = i / ((R1 + 2) * 34);
    int rem = i - ic * (R1 + 2) * 34;
    int r   = rem / 34;
    int cc  = rem - r * 34;
    int gr  = chunk * R1 + r - 1;
    int gc  = wh * WS1 + cc - 1;
    float val = 0.f;
    if ((unsigned)gr < H && (unsigned)gc < W)
      val = rawb[ic * H * W + gr * W + gc];
    t[ic][r][cc] = val;
  }
  __syncthreads();

  const int rp  = tid >> 5;
  const int grp = tid & 31;
  float wt[2][27], A[2], Bc[2];
#pragma unroll
  for (int g = 0; g < 2; ++g) {
    int c = grp * 2 + g;
#pragma unroll
    for (int k = 0; k < 27; ++k) wt[g][k] = wconv[c * 27 + k];
    float sc = g1[c] * rsqrtf(v1[c] + EPSV);
    A[g]  = sc;
    Bc[g] = (bconv[c] - m1[c]) * sc + be1[c];
  }

  f4 cur[CIN][4], nxt[CIN][4];
#pragma unroll
  for (int ic = 0; ic < CIN; ++ic)
#pragma unroll
    for (int r = 0; r < 4; ++r) cur[ic][r] = *(const f4*)&t[ic][2 * rp + r][0];

  float acc0 = 0.f, acc1 = 0.f;
#pragma unroll
  for (int j = 0; j < 8; ++j) {
#pragma unroll
    for (int ic = 0; ic < CIN; ++ic)
#pragma unroll
      for (int r = 0; r < 4; ++r) nxt[ic][r] = *(const f4*)&t[ic][2 * rp + r][4 * j + 4];

    float v[2][2][4];
#pragma unroll
    for (int q = 0; q < 2; ++q)
#pragma unroll
      for (int g = 0; g < 2; ++g)
#pragma unroll
        for (int p = 0; p < 4; ++p) v[q][g][p] = 0.f;

#pragma unroll
    for (int ic = 0; ic < CIN; ++ic) {
#pragma unroll
      for (int q = 0; q < 2; ++q) {
#pragma unroll
        for (int kh = 0; kh < 3; ++kh) {
          f4 a  = cur[ic][q + kh];
          f4 bb = nxt[ic][q + kh];
#pragma unroll
          for (int p = 0; p < 4; ++p) {
#pragma unroll
            for (int kw = 0; kw < 3; ++kw) {
              float e = (p + kw < 4) ? a[p + kw] : bb[p + kw - 4];
              v[q][0][p] += e * wt[0][ic * 9 + kh * 3 + kw];
              v[q][1][p] += e * wt[1][ic * 9 + kh * 3 + kw];
            }
          }
        }
      }
    }
#pragma unroll
    for (int q = 0; q < 2; ++q)
#pragma unroll
      for (int p = 0; p < 4; ++p) {
        acc0 += fmaxf(v[q][0][p] * A[0] + Bc[0], 0.f);
        acc1 += fmaxf(v[q][1][p] * A[1] + Bc[1], 0.f);
      }
#pragma unroll
    for (int ic = 0; ic < CIN; ++ic)
#pragma unroll
      for (int r = 0; r < 4; ++r) cur[ic][r] = nxt[ic][r];
  }

  __shared__ float red[4][C1];
  red[rp][grp * 2]     = acc0;
  red[rp][grp * 2 + 1] = acc1;
  __syncthreads();
  if (tid < C1) {
    float s = red[0][tid] + red[1][tid] + red[2][tid] + red[3][tid];
    partial[((size_t)((b * 16 + chunk) * 4 + wh)) * C1 + tid] = s;
  }
}

// ---------------------------------------------------------------------------
// Kernel 2: pool mean -> dense + BN -> softmax over C. Writes padded stride 28.
// ---------------------------------------------------------------------------
#define NCH 64

__global__ __launch_bounds__(256) void k2_filter(
    const float* __restrict__ partial, const float* __restrict__ wf,
    const float* __restrict__ bf, const float* __restrict__ g2,
    const float* __restrict__ be2, const float* __restrict__ m2,
    const float* __restrict__ v2, float* __restrict__ filt)
{
  const int b  = blockIdx.x / KK;
  const int kk = blockIdx.x - b * KK;
  const int c  = threadIdx.x;

  __shared__ float feat[C1];
  if (c < C1) {
    float s = 0.f;
#pragma unroll
    for (int ch = 0; ch < NCH; ++ch)
      s += partial[((size_t)b * NCH + ch) * C1 + c];
    feat[c] = s * (1.f / (H * W));
  }
  __syncthreads();

  const int idx = c * KK + kk;
  float v = bf[idx];
  const float* wr = wf + (size_t)idx * C1;
#pragma unroll
  for (int j = 0; j < C1; ++j) v += feat[j] * wr[j];
  v = (v - m2[idx]) * (g2[idx] * rsqrtf(v2[idx] + EPSV)) + be2[idx];

  __shared__ float red[256];
  red[c] = v;
  __syncthreads();
#pragma unroll
  for (int s = 128; s > 0; s >>= 1) {
    if (c < s) red[c] = fmaxf(red[c], red[c + s]);
    __syncthreads();
  }
  float mx = red[0];
  __syncthreads();
  float e = expf(v - mx);
  red[c] = e;
  __syncthreads();
#pragma unroll
  for (int s = 128; s > 0; s >>= 1) {
    if (c < s) red[c] += red[c + s];
    __syncthreads();
  }
  filt[((size_t)b * C + c) * FSTR + kk] = e / red[0];
}

// ---------------------------------------------------------------------------
// Kernel 3: per-sample dynamic depthwise 5x5 conv, reflect pad 2.
// Persistent 2-plane blocks, 4 sub-tiles of 64 rows, double-buffered LDS,
// async split staging (issue loads -> compute current -> drain+ds_write).
// 512 thr; LDS 2x(68x132)x4B = 71.8 KB -> 2 blocks/CU. Grid 2048, XCD swizzle.
// ---------------------------------------------------------------------------
#define THS 68
#define TW3 132

// issue global loads for sub-tile (plane base xpq, row origin r0q) into regs
#define LOADSUB(xpq, r0q)                                                     \
  {                                                                           \
    _Pragma("unroll") for (int k = 0; k < 5; ++k) {                           \
      int idx = tid + (k << 9);                                               \
      if (k < 4 || tid < 128) {                                               \
        int r = idx >> 5, g = idx & 31;                                       \
        int gr = (r0q) + r - 2;                                               \
        gr = gr < 0 ? -gr : (gr >= H ? 2 * H - 2 - gr : gr);                  \
        stg[k] = *(const f4*)&(xpq)[gr * W + (g << 2)];                       \
      }                                                                       \
    }                                                                         \
    if (tid < THS * 4) {                                                      \
      int r = tid >> 2, c = tid & 3;                                          \
      int gc = (c == 0) ? 2 : (c == 1) ? 1 : (c == 2) ? 126 : 125;            \
      int gr = (r0q) + r - 2;                                                 \
      gr = gr < 0 ? -gr : (gr >= H ? 2 * H - 2 - gr : gr);                    \
      hstg = (xpq)[gr * W + gc];                                              \
    }                                                                         \
  }

// drain + write staged regs into LDS buffer bufi (with +2 column shift)
#define WRITESUB(bufi)                                                        \
  {                                                                           \
    _Pragma("unroll") for (int k = 0; k < 5; ++k) {                           \
      int idx = tid + (k << 9);                                               \
      if (k < 4 || tid < 128) {                                               \
        int r = idx >> 5, g = idx & 31;                                       \
        f2 lo = {stg[k][0], stg[k][1]};                                       \
        f2 hi = {stg[k][2], stg[k][3]};                                       \
        *(f2*)&t[bufi][r][(g << 2) + 2] = lo;                                 \
        *(f2*)&t[bufi][r][(g << 2) + 4] = hi;                                 \
      }                                                                       \
    }                                                                         \
    if (tid < THS * 4) {                                                      \
      int r = tid >> 2, c = tid & 3;                                          \
      int cc = (c == 0) ? 0 : (c == 1) ? 1 : (c == 2) ? 130 : 131;            \
      t[bufi][r][cc] = hstg;                                                  \
    }                                                                         \
  }

// compute 64 output rows of sub-tile from LDS buffer bufi, NT-store
#define COMPUTE(bufi, opq, r0q, FV)                                           \
  {                                                                           \
    const int w  = (tid & 31) << 2;                                           \
    const int rb = (tid >> 5) << 2;                                           \
    f4 acc[4];                                                                \
    _Pragma("unroll") for (int q = 0; q < 4; ++q)                             \
      acc[q] = (f4){0.f, 0.f, 0.f, 0.f};                                      \
    _Pragma("unroll") for (int tr = 0; tr < 8; ++tr) {                        \
      f4 a  = *(const f4*)&t[bufi][rb + tr][w];                               \
      f4 bb = *(const f4*)&t[bufi][rb + tr][w + 4];                           \
      _Pragma("unroll") for (int q = 0; q < 4; ++q) {                         \
        if (tr - q < 0 || tr - q > 4) continue;                               \
        const int ki = tr - q;                                                \
        _Pragma("unroll") for (int p = 0; p < 4; ++p) {                       \
          _Pragma("unroll") for (int j = 0; j < 5; ++j) {                     \
            float e = (p + j < 4) ? a[p + j] : bb[p + j - 4];                 \
            const int kq = ki * 5 + j;                                        \
            acc[q][p] += e * FV[kq >> 2][kq & 3];                             \
          }                                                                   \
        }                                                                     \
      }                                                                       \
    }                                                                         \
    _Pragma("unroll") for (int q = 0; q < 4; ++q)                             \
      __builtin_nontemporal_store(acc[q],                                     \
          (f4*)&(opq)[((r0q) + rb + q) * W + w]);                             \
  }

__global__ __launch_bounds__(512) void k3_dwconv(
    const float* __restrict__ x, const float* __restrict__ filt,
    float* __restrict__ out)
{
  const int bid = blockIdx.x;
  const int swz = (bid & 7) * 256 + (bid >> 3);   // 2048 % 8 == 0, bijective
  const int pl0 = swz << 1;                        // planes pl0, pl0+1
  const int tid = threadIdx.x;

  const float* xp0 = x   + (size_t)pl0 * H * W;
  const float* xp1 = xp0 + H * W;
  float*       op0 = out + (size_t)pl0 * H * W;
  float*       op1 = op0 + H * W;
  const float* fp0 = filt + (size_t)pl0 * FSTR;
  const float* fp1 = fp0 + FSTR;

  __shared__ __align__(16) float t[2][THS][TW3];

  f4 stg[5]; float hstg = 0.f;
  f4 fvA[7], fvB[7];
#pragma unroll
  for (int i = 0; i < 7; ++i) fvA[i] = *(const f4*)&fp0[i << 2];

  // prologue: stage sub 0 (plane 0, rows 0..63)
  LOADSUB(xp0, 0)
  WRITESUB(0)
  __syncthreads();

  // s = 0: compute sub0 | prefetch sub1
  LOADSUB(xp0, 64)
  COMPUTE(0, op0, 0, fvA)
  WRITESUB(1)
  __syncthreads();

  // s = 1: compute sub1 | prefetch sub2 + plane-1 filter
  LOADSUB(xp1, 0)
#pragma unroll
  for (int i = 0; i < 7; ++i) fvB[i] = *(const f4*)&fp1[i << 2];
  COMPUTE(1, op0, 64, fvA)
  WRITESUB(0)
  __syncthreads();

  // s = 2: compute sub2 | prefetch sub3
  LOADSUB(xp1, 64)
  COMPUTE(0, op1, 0, fvB)
  WRITESUB(1)
  __syncthreads();

  // s = 3: compute sub3
  COMPUTE(1, op1, 64, fvB)
}

// ---------------------------------------------------------------------------
extern "C" void kernel_launch(void* const* d_in, const int* in_sizes, int n_in,
                              void* d_out, int out_size, void* d_ws, size_t ws_size,
                              hipStream_t stream) {
  const float* x_feat = (const float*)d_in[0];
  const float* raw    = (const float*)d_in[1];
  const float* wconv  = (const float*)d_in[2];
  const float* bconv  = (const float*)d_in[3];
  const float* g1     = (const float*)d_in[4];
  const float* be1    = (const float*)d_in[5];
  const float* m1     = (const float*)d_in[6];
  const float* v1     = (const float*)d_in[7];
  const float* wf     = (const float*)d_in[8];
  const float* bf     = (const float*)d_in[9];
  const float* g2     = (const float*)d_in[10];
  const float* be2    = (const float*)d_in[11];
  const float* m2     = (const float*)d_in[12];
  const float* v2     = (const float*)d_in[13];
  float* out = (float*)d_out;

  float* partial = (float*)d_ws;                    // B*NCH*C1 floats
  float* filt    = partial + B * NCH * C1;          // B*C*FSTR floats

  k1_conv_pool<<<B * 16 * 4, 128, 0, stream>>>(raw, wconv, bconv, g1, be1, m1, v1, partial);
  k2_filter  <<<B * KK, 256, 0, stream>>>(partial, wf, bf, g2, be2, m2, v2, filt);
  k3_dwconv  <<<B * C / 2, 512, 0, stream>>>(x_feat, filt, out);
}